// Round 5
// baseline (424.438 us; speedup 1.0000x reference)
//
#include <hip/hip_runtime.h>
#include <hip/hip_bf16.h>

// Problem constants
#define D_DIM   25088
#define B_ROWS  2048
#define C_CLS   100
#define NT      7            // 7 tiles of 16 cols -> 112 padded classes
#define NPAD    112
#define KSTEPS_TOTAL 784     // 25088 / 32
#define OUTER   98           // K-splits (grid.y)
#define KW      8            // K-steps per block: 784 / 98
#define PREP_G  4
#define EPS     1e-8f

typedef __bf16 bf16x8 __attribute__((ext_vector_type(8)));
typedef float  f32x4  __attribute__((ext_vector_type(4)));

// RNE float->bf16, pack two into one dword
__device__ __forceinline__ unsigned bfpack2(float lo, float hi) {
    unsigned a = __builtin_bit_cast(unsigned, lo);
    unsigned b = __builtin_bit_cast(unsigned, hi);
    a += 0x7FFFu + ((a >> 16) & 1u);
    b += 0x7FFFu + ((b >> 16) & 1u);
    return (a >> 16) | (b & 0xFFFF0000u);
}

// ---------------- prep: pack weight into MFMA B-fragment order + partial sumsq ----
// Thread tid = t*64 + quad*16 + n produces the uint4 fragment for class c=t*16+n,
// k = gstep*32 + quad*8 .. +8. wpack[gstep*448 + tid] -> fully coalesced stores.
__global__ __launch_bounds__(448) void prep_kernel(const float* __restrict__ w,
                                                   float* __restrict__ wnorm2,
                                                   uint4* __restrict__ wpack) {
    int tid  = threadIdx.x;
    int t    = tid >> 6;
    int quad = (tid >> 4) & 3;
    int n    = tid & 15;
    int c    = t * 16 + n;
    bool real = (c < C_CLS);
    const float* row = w + (size_t)c * D_DIM + quad * 8;
    float s = 0.f;
#pragma unroll
    for (int g = 0; g < PREP_G; ++g) {
        int gstep = blockIdx.x * PREP_G + g;
        f32x4 v0 = {0.f,0.f,0.f,0.f}, v1 = {0.f,0.f,0.f,0.f};
        if (real) {
            v0 = *(const f32x4*)(row + gstep * 32);
            v1 = *(const f32x4*)(row + gstep * 32 + 4);
        }
        s += v0[0]*v0[0] + v0[1]*v0[1] + v0[2]*v0[2] + v0[3]*v0[3]
           + v1[0]*v1[0] + v1[1]*v1[1] + v1[2]*v1[2] + v1[3]*v1[3];
        uint4 o;
        o.x = bfpack2(v0[0], v0[1]);
        o.y = bfpack2(v0[2], v0[3]);
        o.z = bfpack2(v1[0], v1[1]);
        o.w = bfpack2(v1[2], v1[3]);
        wpack[(size_t)gstep * 448 + tid] = o;
    }
    s += __shfl_xor(s, 16, 64);
    s += __shfl_xor(s, 32, 64);
    if (quad == 0 && real) atomicAdd(&wnorm2[c], s);
}

// ---------------- main GEMM ----------------
// Block = 4 waves, SAME K-slice, different M: wave w owns rows blk.x*128 + w*32 .. +32
// (two 16-row MFMA fragments -> each B fragment reused 2x in registers, 4x via L1
// across the block's waves). B traffic from L2/L3: 784*7KB * (2048/128) = 90 MB
// (was 719 MB with 16 rows/wave -- the R1-R4 ~120us fixed point).
__global__ __launch_bounds__(256, 3) void gemm_kernel(const float* __restrict__ feat,
                                                      const uint4* __restrict__ wpack,
                                                      float* __restrict__ pred,
                                                      float* __restrict__ fnorm2) {
    int tid  = threadIdx.x;
    int wave = tid >> 6, lane = tid & 63;
    int m = lane & 15, quad = lane >> 4;
    int rbase = blockIdx.x * 128 + wave * 32;
    int row0 = rbase + m;
    int gstep0 = blockIdx.y * KW;

    const float* pA0 = feat + (size_t)row0 * D_DIM + gstep0 * 32 + quad * 8;
    const float* pA1 = pA0 + 16 * D_DIM;
    const uint4* pB  = wpack + (size_t)gstep0 * 448 + lane;

    f32x4 acc0[NT], acc1[NT];
#pragma unroll
    for (int t = 0; t < NT; ++t) {
        acc0[t] = (f32x4){0.f,0.f,0.f,0.f};
        acc1[t] = (f32x4){0.f,0.f,0.f,0.f};
    }
    float sq0 = 0.f, sq1 = 0.f;

#pragma unroll
    for (int s = 0; s < KW; ++s) {
        f32x4 a00 = *(const f32x4*)(pA0 + s * 32);
        f32x4 a01 = *(const f32x4*)(pA0 + s * 32 + 4);
        f32x4 a10 = *(const f32x4*)(pA1 + s * 32);
        f32x4 a11 = *(const f32x4*)(pA1 + s * 32 + 4);
        uint4 bfr[NT];
#pragma unroll
        for (int t = 0; t < NT; ++t) bfr[t] = pB[s * 448 + t * 64];

        sq0 += a00[0]*a00[0] + a00[1]*a00[1] + a00[2]*a00[2] + a00[3]*a00[3]
             + a01[0]*a01[0] + a01[1]*a01[1] + a01[2]*a01[2] + a01[3]*a01[3];
        sq1 += a10[0]*a10[0] + a10[1]*a10[1] + a10[2]*a10[2] + a10[3]*a10[3]
             + a11[0]*a11[0] + a11[1]*a11[1] + a11[2]*a11[2] + a11[3]*a11[3];

        uint4 ap0, ap1;
        ap0.x = bfpack2(a00[0], a00[1]);
        ap0.y = bfpack2(a00[2], a00[3]);
        ap0.z = bfpack2(a01[0], a01[1]);
        ap0.w = bfpack2(a01[2], a01[3]);
        ap1.x = bfpack2(a10[0], a10[1]);
        ap1.y = bfpack2(a10[2], a10[3]);
        ap1.z = bfpack2(a11[0], a11[1]);
        ap1.w = bfpack2(a11[2], a11[3]);
        bf16x8 af0 = __builtin_bit_cast(bf16x8, ap0);
        bf16x8 af1 = __builtin_bit_cast(bf16x8, ap1);
#pragma unroll
        for (int t = 0; t < NT; ++t) {
            bf16x8 bb = __builtin_bit_cast(bf16x8, bfr[t]);
            acc0[t] = __builtin_amdgcn_mfma_f32_16x16x32_bf16(af0, bb, acc0[t], 0, 0, 0);
            acc1[t] = __builtin_amdgcn_mfma_f32_16x16x32_bf16(af1, bb, acc1[t], 0, 0, 0);
        }
    }

    // sumsq: reduce across the 4 quads that share each row
    sq0 += __shfl_xor(sq0, 16, 64);
    sq0 += __shfl_xor(sq0, 32, 64);
    sq1 += __shfl_xor(sq1, 16, 64);
    sq1 += __shfl_xor(sq1, 32, 64);
    if (quad == 0) {
        atomicAdd(&fnorm2[row0], sq0);
        atomicAdd(&fnorm2[row0 + 16], sq1);
    }

    // C/D layout (16x16x32 bf16): col = t*16 + m, row = quad*4 + r
#pragma unroll
    for (int t = 0; t < NT; ++t) {
#pragma unroll
        for (int r = 0; r < 4; ++r) {
            int orow = rbase + quad * 4 + r;
            int ocol = t * 16 + m;
            atomicAdd(&pred[(size_t)orow * NPAD + ocol], acc0[t][r]);
            atomicAdd(&pred[(size_t)(orow + 16) * NPAD + ocol], acc1[t][r]);
        }
    }
}

// ---------------- per-row log-softmax / NLL / argmax: one wave per row ----------------
__global__ __launch_bounds__(256) void finalize_kernel(const float* __restrict__ pred,
                                                       const float* __restrict__ fnorm2,
                                                       const float* __restrict__ wnorm2,
                                                       const int* __restrict__ label,
                                                       float* __restrict__ scal) {
    int row = (blockIdx.x * 256 + threadIdx.x) >> 6;
    int lane = threadIdx.x & 63;
    if (row >= B_ROWS) return;
    float finv = 10.0f / fmaxf(sqrtf(fnorm2[row]), EPS);
    const float* pr = pred + (size_t)row * NPAD;

    int c0 = lane, c1 = lane + 64;
    float l0 = -1e30f, l1 = -1e30f;
    if (c0 < C_CLS) l0 = pr[c0] * (finv / fmaxf(sqrtf(wnorm2[c0]), EPS));
    if (c1 < C_CLS) l1 = pr[c1] * (finv / fmaxf(sqrtf(wnorm2[c1]), EPS));

    // argmax (keep smaller index on ties)
    float mx = l0; int am = c0;
    if (l1 > mx) { mx = l1; am = c1; }
    for (int o = 1; o < 64; o <<= 1) {
        float om = __shfl_xor(mx, o, 64);
        int   oa = __shfl_xor(am, o, 64);
        if (om > mx || (om == mx && oa < am)) { mx = om; am = oa; }
    }
    float se = expf(l0 - mx) + expf(l1 - mx);
    for (int o = 1; o < 64; o <<= 1) se += __shfl_xor(se, o, 64);

    int lab = label[row];
    int labc = (lab < 0) ? 0 : lab;
    float lv = (labc >= 64) ? l1 : l0;
    float ll = __shfl(lv, labc & 63, 64);

    if (lane == 0 && lab >= 0) {
        float lse = mx + logf(se);
        atomicAdd(&scal[0], lse - ll);
        atomicAdd(&scal[1], (am == lab) ? 1.f : 0.f);
        atomicAdd(&scal[2], 1.f);
    }
}

__global__ void out_kernel(const float* __restrict__ scal, float* __restrict__ out) {
    out[0] = scal[0] / fmaxf(scal[2], 1.0f);
    out[1] = scal[1] / (scal[2] + 1e-10f);
}

// Workspace layout (bytes):
//   [0, 917504)          pred:   2048*112 f32 (zeroed, atomic-accumulated)
//   [917504, 925696)     fnorm2: 2048 f32 (zeroed)
//   [925696, 925712)     scalars: 4 f32 (zeroed)
//   [925712, 926160)     wnorm2: 112 f32 (zeroed)
//   [926720, 6546432)    wpack:  784*448 uint4 bf16 B-fragments
extern "C" void kernel_launch(void* const* d_in, const int* in_sizes, int n_in,
                              void* d_out, int out_size, void* d_ws, size_t ws_size,
                              hipStream_t stream) {
    const float* feat   = (const float*)d_in[0];
    const int*   label  = (const int*)d_in[1];
    const float* weight = (const float*)d_in[2];
    float* out = (float*)d_out;

    char* ws = (char*)d_ws;
    float* pred   = (float*)(ws);
    float* fnorm2 = (float*)(ws + 917504);
    float* scal   = (float*)(ws + 925696);
    float* wnorm2 = (float*)(ws + 925712);
    uint4* wpack  = (uint4*)(ws + 926720);

    hipMemsetAsync(ws, 0, 926160, stream);
    prep_kernel<<<KSTEPS_TOTAL / PREP_G, 448, 0, stream>>>(weight, wnorm2, wpack);
    gemm_kernel<<<dim3(B_ROWS / 128, OUTER), 256, 0, stream>>>(feat, wpack, pred, fnorm2);
    finalize_kernel<<<B_ROWS / 4, 256, 0, stream>>>(pred, fnorm2, wnorm2, label, scal);
    out_kernel<<<1, 1, 0, stream>>>(scal, out);
}